// Round 7
// baseline (59.265 us; speedup 1.0000x reference)
//
#include <hip/hip_runtime.h>

#define K_OFF 27
#define CIN   2
#define COUT  16
#define BLK   256
#define WPB   4                 // waves per block
#define IPW   (64 * K_OFF)      // 1728 ints per wave tile
#define NB    8                 // pair-loop batch width (covers ~97.6% of tiles in one pass)

typedef __attribute__((address_space(3))) unsigned int lds_u32;
typedef __attribute__((address_space(1))) const unsigned int g_u32;

__global__ __launch_bounds__(BLK, 5) void spconv_kernel(
    const float* __restrict__ feats,   // [N][2]
    const float* __restrict__ w,       // [27][2][16]
    const int*   __restrict__ nbr,     // [N][27]
    float*       __restrict__ out,     // [N][16]
    int n_pts)
{
    __shared__ int    s_idx[WPB * IPW];   // 27648 B, wave-private staging
    __shared__ float4 s_w[8 * K_OFF];     // 3456 B, W as [q][k] float4

    const int t    = threadIdx.x;
    const int lane = t & 63;
    const int wv   = t >> 6;
    const int tile = blockIdx.x * WPB + wv;
    const int p    = tile * 64 + lane;

    // ---- W -> LDS, [q][k] layout ----
    if (t < 8 * K_OFF) {
        const int k = t >> 3, q = t & 7;
        s_w[q * K_OFF + k] = reinterpret_cast<const float4*>(w)[t];
    }

    const bool full = ((tile + 1) * 64 <= n_pts);   // wave-uniform
    if (full) {
        const int* src = nbr + (size_t)tile * IPW;
        int*       dst = s_idx + wv * IPW;
        #pragma unroll
        for (int j = 0; j < 6; ++j) {
            __builtin_amdgcn_global_load_lds(
                (g_u32*)(src + j * 256 + lane * 4),
                (lds_u32*)(dst + j * 256), 16, 0, 0);
        }
        if (lane < 48) {
            __builtin_amdgcn_global_load_lds(
                (g_u32*)(src + 6 * 256 + lane * 4),
                (lds_u32*)(dst + 6 * 256), 16, 0, 0);
        }
    }
    __syncthreads();   // drains vmcnt (stage) + lgkm (W writes)

    float acc[COUT];
    #pragma unroll
    for (int d = 0; d < COUT; ++d) acc[d] = 0.f;

    const float2* feats2 = reinterpret_cast<const float2*>(feats);
    const int* rowp = s_idx + wv * IPW + lane * K_OFF;

    // ---- scan: per-lane validity bitmap (stride-27 b32 reads, conflict-free) ----
    unsigned bm = 0;
    if (full) {
        #pragma unroll
        for (int k = 0; k < K_OFF; ++k)
            bm |= (rowp[k] >= 0) ? (1u << k) : 0u;
    }

    // wave-max trip count
    int mx = __popc(bm);
    #pragma unroll
    for (int off = 32; off; off >>= 1) mx = max(mx, __shfl_xor(mx, off, 64));

    // ---- batched compacted pair loop: NB gathers in flight per pass ----
    for (int j0 = 0; j0 < mx; j0 += NB) {
        // phase 0: extract NB k's (pure VALU, no memory)
        int  kk[NB];
        bool al[NB];
        #pragma unroll
        for (int j = 0; j < NB; ++j) {
            al[j] = (bm != 0);
            kk[j] = al[j] ? (int)__builtin_ctz(bm) : 0;
            bm &= bm - 1;
        }
        // phase 1: NB independent idx reads from LDS
        int idx[NB];
        #pragma unroll
        for (int j = 0; j < NB; ++j) idx[j] = rowp[kk[j]];
        // phase 2: NB independent feats gathers (all in flight)
        float2 f[NB];
        #pragma unroll
        for (int j = 0; j < NB; ++j) f[j] = feats2[al[j] && idx[j] > 0 ? idx[j] : 0];
        // phase 3: FMAs
        #pragma unroll
        for (int j = 0; j < NB; ++j) {
            const float fm = al[j] ? 1.0f : 0.0f;
            const float fx = f[j].x * fm, fy = f[j].y * fm;
            const int k = kk[j];
            #pragma unroll
            for (int q = 0; q < 4; ++q) {
                const float4 wa = s_w[q * K_OFF + k];        // cin=0
                const float4 wb = s_w[(q + 4) * K_OFF + k];  // cin=1
                acc[q*4+0] = fmaf(fy, wb.x, fmaf(fx, wa.x, acc[q*4+0]));
                acc[q*4+1] = fmaf(fy, wb.y, fmaf(fx, wa.y, acc[q*4+1]));
                acc[q*4+2] = fmaf(fy, wb.z, fmaf(fx, wa.z, acc[q*4+2]));
                acc[q*4+3] = fmaf(fy, wb.w, fmaf(fx, wa.w, acc[q*4+3]));
            }
        }
    }

    // ---- partial-tile fallback: dense masked loop, direct global idx reads ----
    if (!full) {
        const bool pv = (p < n_pts);
        for (int k = 0; k < K_OFF; ++k) {
            const int idx = pv ? nbr[(size_t)p * K_OFF + k] : -1;
            const float fm = (idx >= 0) ? 1.0f : 0.0f;
            const float2 f = feats2[idx > 0 ? idx : 0];
            const float fx = f.x * fm, fy = f.y * fm;
            #pragma unroll
            for (int q = 0; q < 4; ++q) {
                const float4 wa = s_w[q * K_OFF + k];
                const float4 wb = s_w[(q + 4) * K_OFF + k];
                acc[q*4+0] = fmaf(fy, wb.x, fmaf(fx, wa.x, acc[q*4+0]));
                acc[q*4+1] = fmaf(fy, wb.y, fmaf(fx, wa.y, acc[q*4+1]));
                acc[q*4+2] = fmaf(fy, wb.z, fmaf(fx, wa.z, acc[q*4+2]));
                acc[q*4+3] = fmaf(fy, wb.w, fmaf(fx, wa.w, acc[q*4+3]));
            }
        }
    }

    if (p < n_pts) {
        float4* o = reinterpret_cast<float4*>(out + (size_t)p * COUT);
        o[0] = make_float4(acc[0],  acc[1],  acc[2],  acc[3]);
        o[1] = make_float4(acc[4],  acc[5],  acc[6],  acc[7]);
        o[2] = make_float4(acc[8],  acc[9],  acc[10], acc[11]);
        o[3] = make_float4(acc[12], acc[13], acc[14], acc[15]);
    }
}

extern "C" void kernel_launch(void* const* d_in, const int* in_sizes, int n_in,
                              void* d_out, int out_size, void* d_ws, size_t ws_size,
                              hipStream_t stream) {
    const float* feats = (const float*)d_in[0];
    const float* w     = (const float*)d_in[1];
    const int*   nbr   = (const int*)d_in[2];
    float*       out   = (float*)d_out;

    const int n_pts   = in_sizes[0] / CIN;
    const int n_tiles = (n_pts + 63) / 64;
    const int grid    = (n_tiles + WPB - 1) / WPB;

    spconv_kernel<<<grid, BLK, 0, stream>>>(feats, w, nbr, out, n_pts);
}

// Round 8
// 55.759 us; speedup vs baseline: 1.0629x; 1.0629x over previous
//
#include <hip/hip_runtime.h>

#define K_OFF 27
#define CIN   2
#define COUT  16
#define BLK   256
#define WPB   4                 // waves per block
#define IPW   (64 * K_OFF)      // 1728 ints per wave tile
#define NB    6                 // spill-safe batch width

typedef __attribute__((address_space(3))) unsigned int lds_u32;
typedef __attribute__((address_space(1))) const unsigned int g_u32;

__device__ __forceinline__ void stage_tile(const int* __restrict__ nbr,
                                           int tile, int* dst, int lane) {
    const int* src = nbr + (size_t)tile * IPW;
    #pragma unroll
    for (int j = 0; j < 6; ++j)
        __builtin_amdgcn_global_load_lds((g_u32*)(src + j * 256 + lane * 4),
                                         (lds_u32*)(dst + j * 256), 16, 0, 0);
    if (lane < 48)
        __builtin_amdgcn_global_load_lds((g_u32*)(src + 6 * 256 + lane * 4),
                                         (lds_u32*)(dst + 6 * 256), 16, 0, 0);
}

__global__ __launch_bounds__(BLK, 2) void spconv_kernel(
    const float* __restrict__ feats,   // [N][2]
    const float* __restrict__ w,       // [27][2][16]
    const int*   __restrict__ nbr,     // [N][27]
    float*       __restrict__ out,     // [N][16]
    int n_pts, int n_tiles)
{
    __shared__ int    s_idx[WPB * 2 * IPW];   // 55296 B: per-wave double buffer
    __shared__ float4 s_w[8 * K_OFF];         // 3456 B, W as [q][k] float4

    const int t    = threadIdx.x;
    const int lane = t & 63;
    const int wv   = t >> 6;

    if (t < 8 * K_OFF) {                      // W -> LDS, [q][k] layout
        const int k = t >> 3, q = t & 7;
        s_w[q * K_OFF + k] = reinterpret_cast<const float4*>(w)[t];
    }
    __syncthreads();                          // once; no barriers in the loop

    const int n_waves = gridDim.x * WPB;
    int* bufA = s_idx + wv * (2 * IPW);
    int* bufB = bufA + IPW;

    const float2* feats2 = reinterpret_cast<const float2*>(feats);

    int tile = blockIdx.x * WPB + wv;
    if (tile >= n_tiles) return;

    if ((tile + 1) * 64 <= n_pts) stage_tile(nbr, tile, bufA, lane);
    int cur = 0;

    while (true) {
        // current buffer's DMA (and last tile's gathers/stores) complete
        asm volatile("s_waitcnt vmcnt(0)" ::: "memory");
        __builtin_amdgcn_sched_barrier(0);
        __builtin_amdgcn_wave_barrier();

        const int nxt = tile + n_waves;
        // issue-early: next tile's stage into the other buffer, rides under compute
        if (nxt < n_tiles && (nxt + 1) * 64 <= n_pts)
            stage_tile(nbr, nxt, cur ? bufA : bufB, lane);

        int* buf = cur ? bufB : bufA;
        const bool tfull = ((tile + 1) * 64 <= n_pts);

        float acc[COUT];
        #pragma unroll
        for (int d = 0; d < COUT; ++d) acc[d] = 0.f;

        if (tfull) {
            const int* rowp = buf + lane * K_OFF;
            // scan: validity bitmap (stride-27 b32, 2-way = free)
            unsigned bm = 0;
            #pragma unroll
            for (int k = 0; k < K_OFF; ++k)
                bm |= (rowp[k] >= 0) ? (1u << k) : 0u;
            int mx = __popc(bm);
            #pragma unroll
            for (int off = 32; off; off >>= 1) mx = max(mx, __shfl_xor(mx, off, 64));

            for (int j0 = 0; j0 < mx; j0 += NB) {
                int   kk[NB]; float fm[NB];
                #pragma unroll
                for (int j = 0; j < NB; ++j) {
                    const bool alive = (bm != 0);
                    kk[j] = alive ? (int)__builtin_ctz(bm) : 0;
                    fm[j] = alive ? 1.0f : 0.0f;
                    bm &= bm - 1;
                }
                int idx[NB];
                #pragma unroll
                for (int j = 0; j < NB; ++j) idx[j] = rowp[kk[j]];
                float2 f[NB];
                #pragma unroll
                for (int j = 0; j < NB; ++j)
                    f[j] = feats2[(fm[j] > 0.f && idx[j] > 0) ? idx[j] : 0];
                #pragma unroll
                for (int j = 0; j < NB; ++j) {
                    const float fx = f[j].x * fm[j], fy = f[j].y * fm[j];
                    const int k = kk[j];
                    #pragma unroll
                    for (int q = 0; q < 4; ++q) {
                        const float4 wa = s_w[q * K_OFF + k];
                        const float4 wb = s_w[(q + 4) * K_OFF + k];
                        acc[q*4+0] = fmaf(fy, wb.x, fmaf(fx, wa.x, acc[q*4+0]));
                        acc[q*4+1] = fmaf(fy, wb.y, fmaf(fx, wa.y, acc[q*4+1]));
                        acc[q*4+2] = fmaf(fy, wb.z, fmaf(fx, wa.z, acc[q*4+2]));
                        acc[q*4+3] = fmaf(fy, wb.w, fmaf(fx, wa.w, acc[q*4+3]));
                    }
                }
            }
        } else {
            // partial tile: dense masked loop, direct global idx reads
            const int p = tile * 64 + lane;
            const bool pv = (p < n_pts);
            for (int k = 0; k < K_OFF; ++k) {
                const int idx = pv ? nbr[(size_t)p * K_OFF + k] : -1;
                const float m = (idx >= 0) ? 1.0f : 0.0f;
                const float2 f = feats2[idx > 0 ? idx : 0];
                const float fx = f.x * m, fy = f.y * m;
                #pragma unroll
                for (int q = 0; q < 4; ++q) {
                    const float4 wa = s_w[q * K_OFF + k];
                    const float4 wb = s_w[(q + 4) * K_OFF + k];
                    acc[q*4+0] = fmaf(fy, wb.x, fmaf(fx, wa.x, acc[q*4+0]));
                    acc[q*4+1] = fmaf(fy, wb.y, fmaf(fx, wa.y, acc[q*4+1]));
                    acc[q*4+2] = fmaf(fy, wb.z, fmaf(fx, wa.z, acc[q*4+2]));
                    acc[q*4+3] = fmaf(fy, wb.w, fmaf(fx, wa.w, acc[q*4+3]));
                }
            }
        }

        const int p = tile * 64 + lane;
        if (p < n_pts) {
            float4* o = reinterpret_cast<float4*>(out + (size_t)p * COUT);
            o[0] = make_float4(acc[0],  acc[1],  acc[2],  acc[3]);
            o[1] = make_float4(acc[4],  acc[5],  acc[6],  acc[7]);
            o[2] = make_float4(acc[8],  acc[9],  acc[10], acc[11]);
            o[3] = make_float4(acc[12], acc[13], acc[14], acc[15]);
        }

        if (nxt >= n_tiles) break;
        tile = nxt;
        cur ^= 1;
    }
}

extern "C" void kernel_launch(void* const* d_in, const int* in_sizes, int n_in,
                              void* d_out, int out_size, void* d_ws, size_t ws_size,
                              hipStream_t stream) {
    const float* feats = (const float*)d_in[0];
    const float* w     = (const float*)d_in[1];
    const int*   nbr   = (const int*)d_in[2];
    float*       out   = (float*)d_out;

    const int n_pts   = in_sizes[0] / CIN;
    const int n_tiles = (n_pts + 63) / 64;
    int grid = (n_tiles + WPB - 1) / WPB;
    if (grid > 512) grid = 512;               // 2 resident blocks/CU, persistent waves

    spconv_kernel<<<grid, BLK, 0, stream>>>(feats, w, nbr, out, n_pts, n_tiles);
}

// Round 9
// 54.576 us; speedup vs baseline: 1.0859x; 1.0217x over previous
//
#include <hip/hip_runtime.h>

#define K_OFF 27
#define CIN   2
#define COUT  16
#define BLK   256
#define WPB   4                 // waves per block
#define IPW   (64 * K_OFF)      // 1728 ints per wave tile
#define NB    8                 // batch width: 8 gathers in flight per wave

typedef __attribute__((address_space(3))) unsigned int lds_u32;
typedef __attribute__((address_space(1))) const unsigned int g_u32;

__global__ __launch_bounds__(BLK, 2) void spconv_kernel(
    const float* __restrict__ feats,   // [N][2]
    const float* __restrict__ w,       // [27][2][16]
    const int*   __restrict__ nbr,     // [N][27]
    float*       __restrict__ out,     // [N][16]
    int n_pts)
{
    __shared__ int    s_idx[WPB * IPW];   // 27648 B, wave-private staging
    __shared__ float4 s_w[8 * K_OFF];     // 3456 B, W as [q][k] float4

    const int t    = threadIdx.x;
    const int lane = t & 63;
    const int wv   = t >> 6;
    const int tile = blockIdx.x * WPB + wv;
    const int p    = tile * 64 + lane;

    // ---- W -> LDS, [q][k] layout ----
    if (t < 8 * K_OFF) {
        const int k = t >> 3, q = t & 7;
        s_w[q * K_OFF + k] = reinterpret_cast<const float4*>(w)[t];
    }

    const bool full = ((tile + 1) * 64 <= n_pts);   // wave-uniform
    if (full) {
        const int* src = nbr + (size_t)tile * IPW;
        int*       dst = s_idx + wv * IPW;
        #pragma unroll
        for (int j = 0; j < 6; ++j) {
            __builtin_amdgcn_global_load_lds(
                (g_u32*)(src + j * 256 + lane * 4),
                (lds_u32*)(dst + j * 256), 16, 0, 0);
        }
        if (lane < 48) {
            __builtin_amdgcn_global_load_lds(
                (g_u32*)(src + 6 * 256 + lane * 4),
                (lds_u32*)(dst + 6 * 256), 16, 0, 0);
        }
    }
    __syncthreads();   // drains vmcnt (stage) + lgkm (W writes)

    float acc[COUT];
    #pragma unroll
    for (int d = 0; d < COUT; ++d) acc[d] = 0.f;

    const float2* feats2 = reinterpret_cast<const float2*>(feats);
    const int* rowp = s_idx + wv * IPW + lane * K_OFF;

    // ---- scan: per-lane validity bitmap (stride-27 b32, conflict-free) ----
    unsigned bm = 0;
    if (full) {
        #pragma unroll
        for (int k = 0; k < K_OFF; ++k)
            bm |= (rowp[k] >= 0) ? (1u << k) : 0u;
    }

    // wave-max trip count
    int mx = __popc(bm);
    #pragma unroll
    for (int off = 32; off; off >>= 1) mx = max(mx, __shfl_xor(mx, off, 64));

    // ---- batched compacted pair loop: NB=8 gathers in flight per pass ----
    for (int j0 = 0; j0 < mx; j0 += NB) {
        int   kk[NB]; float fm[NB];
        #pragma unroll
        for (int j = 0; j < NB; ++j) {
            const bool alive = (bm != 0);
            kk[j] = alive ? (int)__builtin_ctz(bm) : 0;
            fm[j] = alive ? 1.0f : 0.0f;
            bm &= bm - 1;
        }
        int idx[NB];
        #pragma unroll
        for (int j = 0; j < NB; ++j) idx[j] = rowp[kk[j]];
        float2 f[NB];
        #pragma unroll
        for (int j = 0; j < NB; ++j)
            f[j] = feats2[(fm[j] > 0.f && idx[j] > 0) ? idx[j] : 0];
        #pragma unroll
        for (int j = 0; j < NB; ++j) {
            const float fx = f[j].x * fm[j], fy = f[j].y * fm[j];
            const int k = kk[j];
            #pragma unroll
            for (int q = 0; q < 4; ++q) {
                const float4 wa = s_w[q * K_OFF + k];        // cin=0
                const float4 wb = s_w[(q + 4) * K_OFF + k];  // cin=1
                acc[q*4+0] = fmaf(fy, wb.x, fmaf(fx, wa.x, acc[q*4+0]));
                acc[q*4+1] = fmaf(fy, wb.y, fmaf(fx, wa.y, acc[q*4+1]));
                acc[q*4+2] = fmaf(fy, wb.z, fmaf(fx, wa.z, acc[q*4+2]));
                acc[q*4+3] = fmaf(fy, wb.w, fmaf(fx, wa.w, acc[q*4+3]));
            }
        }
    }

    // ---- partial-tile fallback: dense masked loop, direct global idx reads ----
    if (!full) {
        const bool pv = (p < n_pts);
        for (int k = 0; k < K_OFF; ++k) {
            const int idx = pv ? nbr[(size_t)p * K_OFF + k] : -1;
            const float fm2 = (idx >= 0) ? 1.0f : 0.0f;
            const float2 f = feats2[idx > 0 ? idx : 0];
            const float fx = f.x * fm2, fy = f.y * fm2;
            #pragma unroll
            for (int q = 0; q < 4; ++q) {
                const float4 wa = s_w[q * K_OFF + k];
                const float4 wb = s_w[(q + 4) * K_OFF + k];
                acc[q*4+0] = fmaf(fy, wb.x, fmaf(fx, wa.x, acc[q*4+0]));
                acc[q*4+1] = fmaf(fy, wb.y, fmaf(fx, wa.y, acc[q*4+1]));
                acc[q*4+2] = fmaf(fy, wb.z, fmaf(fx, wa.z, acc[q*4+2]));
                acc[q*4+3] = fmaf(fy, wb.w, fmaf(fx, wa.w, acc[q*4+3]));
            }
        }
    }

    if (p < n_pts) {
        float4* o = reinterpret_cast<float4*>(out + (size_t)p * COUT);
        o[0] = make_float4(acc[0],  acc[1],  acc[2],  acc[3]);
        o[1] = make_float4(acc[4],  acc[5],  acc[6],  acc[7]);
        o[2] = make_float4(acc[8],  acc[9],  acc[10], acc[11]);
        o[3] = make_float4(acc[12], acc[13], acc[14], acc[15]);
    }
}

extern "C" void kernel_launch(void* const* d_in, const int* in_sizes, int n_in,
                              void* d_out, int out_size, void* d_ws, size_t ws_size,
                              hipStream_t stream) {
    const float* feats = (const float*)d_in[0];
    const float* w     = (const float*)d_in[1];
    const int*   nbr   = (const int*)d_in[2];
    float*       out   = (float*)d_out;

    const int n_pts   = in_sizes[0] / CIN;
    const int n_tiles = (n_pts + 63) / 64;
    const int grid    = (n_tiles + WPB - 1) / WPB;

    spconv_kernel<<<grid, BLK, 0, stream>>>(feats, w, nbr, out, n_pts);
}

// Round 10
// 53.654 us; speedup vs baseline: 1.1046x; 1.0172x over previous
//
#include <hip/hip_runtime.h>

#define K_OFF 27
#define CIN   2
#define COUT  16
#define BLK   256
#define WPB   4                 // waves per block
#define IPW   (64 * K_OFF)      // 1728 ints per wave tile
#define NB    8                 // batch width: 8 gathers in flight (asm-enforced)

typedef __attribute__((address_space(3))) unsigned int lds_u32;
typedef __attribute__((address_space(1))) const unsigned int g_u32;

__global__ __launch_bounds__(BLK, 2) void spconv_kernel(
    const float* __restrict__ feats,   // [N][2]
    const float* __restrict__ w,       // [27][2][16]
    const int*   __restrict__ nbr,     // [N][27]
    float*       __restrict__ out,     // [N][16]
    int n_pts)
{
    __shared__ int    s_idx[WPB * IPW];   // 27648 B, wave-private staging
    __shared__ float4 s_w[8 * K_OFF];     // 3456 B, W as [q][k] float4

    const int t    = threadIdx.x;
    const int lane = t & 63;
    const int wv   = t >> 6;
    const int tile = blockIdx.x * WPB + wv;
    const int p    = tile * 64 + lane;

    // ---- W -> LDS, [q][k] layout ----
    if (t < 8 * K_OFF) {
        const int k = t >> 3, q = t & 7;
        s_w[q * K_OFF + k] = reinterpret_cast<const float4*>(w)[t];
    }

    const bool full = ((tile + 1) * 64 <= n_pts);   // wave-uniform
    if (full) {
        const int* src = nbr + (size_t)tile * IPW;
        int*       dst = s_idx + wv * IPW;
        #pragma unroll
        for (int j = 0; j < 6; ++j) {
            __builtin_amdgcn_global_load_lds(
                (g_u32*)(src + j * 256 + lane * 4),
                (lds_u32*)(dst + j * 256), 16, 0, 0);
        }
        if (lane < 48) {
            __builtin_amdgcn_global_load_lds(
                (g_u32*)(src + 6 * 256 + lane * 4),
                (lds_u32*)(dst + 6 * 256), 16, 0, 0);
        }
    }
    __syncthreads();   // drains vmcnt (stage) + lgkm (W writes)

    float acc[COUT];
    #pragma unroll
    for (int d = 0; d < COUT; ++d) acc[d] = 0.f;

    const float2* feats2 = reinterpret_cast<const float2*>(feats);
    const int* rowp = s_idx + wv * IPW + lane * K_OFF;

    // ---- scan: per-lane validity bitmap (stride-27 b32, conflict-free) ----
    unsigned bm = 0;
    if (full) {
        #pragma unroll
        for (int k = 0; k < K_OFF; ++k)
            bm |= (rowp[k] >= 0) ? (1u << k) : 0u;
    }

    // wave-max trip count
    int mx = __popc(bm);
    #pragma unroll
    for (int off = 32; off; off >>= 1) mx = max(mx, __shfl_xor(mx, off, 64));

    // ---- batched pair loop: NB gathers clustered via volatile asm ----
    for (int j0 = 0; j0 < mx; j0 += NB) {
        int   kk[NB]; float fm[NB];
        #pragma unroll
        for (int j = 0; j < NB; ++j) {
            const bool alive = (bm != 0);
            kk[j] = alive ? (int)__builtin_ctz(bm) : 0;
            fm[j] = alive ? 1.0f : 0.0f;
            bm &= bm - 1;
        }
        int idx[NB];
        #pragma unroll
        for (int j = 0; j < NB; ++j) idx[j] = rowp[kk[j]];

        // 8 back-to-back global_load_dwordx2 — scheduler cannot reorder volatile asm
        float2 f[NB];
        #pragma unroll
        for (int j = 0; j < NB; ++j) {
            const float2* ap = feats2 + ((fm[j] > 0.f && idx[j] > 0) ? idx[j] : 0);
            asm volatile("global_load_dwordx2 %0, %1, off"
                         : "=v"(f[j]) : "v"(ap));
        }
        asm volatile("s_waitcnt vmcnt(0)" ::: "memory");
        __builtin_amdgcn_sched_barrier(0);   // rule #18: keep FMAs after the waitcnt

        #pragma unroll
        for (int j = 0; j < NB; ++j) {
            const float fx = f[j].x * fm[j], fy = f[j].y * fm[j];
            const int k = kk[j];
            #pragma unroll
            for (int q = 0; q < 4; ++q) {
                const float4 wa = s_w[q * K_OFF + k];        // cin=0
                const float4 wb = s_w[(q + 4) * K_OFF + k];  // cin=1
                acc[q*4+0] = fmaf(fy, wb.x, fmaf(fx, wa.x, acc[q*4+0]));
                acc[q*4+1] = fmaf(fy, wb.y, fmaf(fx, wa.y, acc[q*4+1]));
                acc[q*4+2] = fmaf(fy, wb.z, fmaf(fx, wa.z, acc[q*4+2]));
                acc[q*4+3] = fmaf(fy, wb.w, fmaf(fx, wa.w, acc[q*4+3]));
            }
        }
    }

    // ---- partial-tile fallback: dense masked loop, direct global idx reads ----
    if (!full) {
        const bool pv = (p < n_pts);
        for (int k = 0; k < K_OFF; ++k) {
            const int idx = pv ? nbr[(size_t)p * K_OFF + k] : -1;
            const float fm2 = (idx >= 0) ? 1.0f : 0.0f;
            const float2 f = feats2[idx > 0 ? idx : 0];
            const float fx = f.x * fm2, fy = f.y * fm2;
            #pragma unroll
            for (int q = 0; q < 4; ++q) {
                const float4 wa = s_w[q * K_OFF + k];
                const float4 wb = s_w[(q + 4) * K_OFF + k];
                acc[q*4+0] = fmaf(fy, wb.x, fmaf(fx, wa.x, acc[q*4+0]));
                acc[q*4+1] = fmaf(fy, wb.y, fmaf(fx, wa.y, acc[q*4+1]));
                acc[q*4+2] = fmaf(fy, wb.z, fmaf(fx, wa.z, acc[q*4+2]));
                acc[q*4+3] = fmaf(fy, wb.w, fmaf(fx, wa.w, acc[q*4+3]));
            }
        }
    }

    if (p < n_pts) {
        float4* o = reinterpret_cast<float4*>(out + (size_t)p * COUT);
        o[0] = make_float4(acc[0],  acc[1],  acc[2],  acc[3]);
        o[1] = make_float4(acc[4],  acc[5],  acc[6],  acc[7]);
        o[2] = make_float4(acc[8],  acc[9],  acc[10], acc[11]);
        o[3] = make_float4(acc[12], acc[13], acc[14], acc[15]);
    }
}

extern "C" void kernel_launch(void* const* d_in, const int* in_sizes, int n_in,
                              void* d_out, int out_size, void* d_ws, size_t ws_size,
                              hipStream_t stream) {
    const float* feats = (const float*)d_in[0];
    const float* w     = (const float*)d_in[1];
    const int*   nbr   = (const int*)d_in[2];
    float*       out   = (float*)d_out;

    const int n_pts   = in_sizes[0] / CIN;
    const int n_tiles = (n_pts + 63) / 64;
    const int grid    = (n_tiles + WPB - 1) / WPB;

    spconv_kernel<<<grid, BLK, 0, stream>>>(feats, w, nbr, out, n_pts);
}